// Round 12
// baseline (525.804 us; speedup 1.0000x reference)
//
#include <hip/hip_runtime.h>

#define NB 32
#define NS 512
#define NE 128
#define NU 10000

// ---- workspace layout (int units) ----
#define WS_PREVU 0                 // 16384
#define WS_PREVI 16384             // 16384
#define WS_RCNT  32768             // 3*32: per-(round,b) node counts
#define WS_LCNT  32864             // 32: per-b late counts (contiguous w/ RCNT)
#define WS_GL    32896             // 3*32*512: per-(round,b) t-lists
#define WS_LATE  82048             // 32*512: per-b late t-lists
#define WS_WBF   98432             // 147456 ushorts (bf16 W_stack) = 73728 ints
#define WS_FLAG  172160            // 16384: per-node ready flags

typedef __attribute__((ext_vector_type(8))) short bf16x8;
typedef __attribute__((ext_vector_type(4))) float f32x4;

__device__ __forceinline__ unsigned short f2bf(float f) {
    unsigned int u = __float_as_uint(f);
    u += 0x7fff + ((u >> 16) & 1);   // round-to-nearest-even
    return (unsigned short)(u >> 16);
}

// LDS-only barrier (no vmcnt drain; global ops stay in flight).
#define BARRIER() do { \
    asm volatile("s_waitcnt lgkmcnt(0)" ::: "memory"); \
    __builtin_amdgcn_s_barrier(); \
    __builtin_amdgcn_sched_barrier(0); \
} while (0)

// ---- kernel 1: per-b prep (blocks 0..31) + W->bf16 + flag zero (32..67) ----
__global__ __launch_bounds__(512) void prep_kernel(
    const int* __restrict__ users, const int* __restrict__ items,
    const float* __restrict__ w_ih, const float* __restrict__ w_hh, int* ws)
{
    const int blk = blockIdx.x, tid = threadIdx.x;
    if (blk >= 32) {
        // convw: W_stack row R: R<384 -> w_ih[R,0:128]; R<768 ->
        // w_ih[R-384,128:256]; else w_hh[R-768,:]. 8 elems/thread.
        const int base = (blk - 32) * 4096 + tid * 8;
        const int r = base >> 7, k = base & 127;
        const float* src;
        if (r < 384)      src = w_ih + (size_t)r * 256 + k;
        else if (r < 768) src = w_ih + (size_t)(r - 384) * 256 + 128 + k;
        else              src = w_hh + (size_t)(r - 768) * 128 + k;
        unsigned short* wbf = (unsigned short*)(ws + WS_WBF);
#pragma unroll
        for (int j = 0; j < 8; ++j) wbf[base + j] = f2bf(src[j]);
        const int fidx = (blk - 32) * 512 + tid;
        if (fidx < 16384) ws[WS_FLAG + fidx] = 0;
        return;
    }
    const int b = blk;
    __shared__ int s_u[NS], s_i[NS];
    __shared__ unsigned char s_r[NS];
    __shared__ int cnt[3], s_chg;
    s_u[tid] = users[b * NS + tid];
    s_i[tid] = items[b * NS + tid];
    if (tid < 3) cnt[tid] = 0;
    __syncthreads();
    // backward prev scans, 8-batched to pipeline LDS latency
    const int mu = s_u[tid], mi = s_i[tid];
    int pu = -1, pi = -1;
    for (int u = tid - 1; u >= 0 && pu < 0; u -= 8) {
        int vals[8];
#pragma unroll
        for (int j = 0; j < 8; ++j) {
            const int uu = u - j;
            vals[j] = (uu >= 0) ? s_u[uu] : -1;
        }
#pragma unroll
        for (int j = 0; j < 8; ++j)
            if (pu < 0 && vals[j] == mu) pu = u - j;
    }
    for (int u = tid - 1; u >= 0 && pi < 0; u -= 8) {
        int vals[8];
#pragma unroll
        for (int j = 0; j < 8; ++j) {
            const int uu = u - j;
            vals[j] = (uu >= 0) ? s_i[uu] : -1;
        }
#pragma unroll
        for (int j = 0; j < 8; ++j)
            if (pi < 0 && vals[j] == mi) pi = u - j;
    }
    ws[WS_PREVU + (b << 9) + tid] = pu;
    ws[WS_PREVI + (b << 9) + tid] = pi;
    // round relaxation (monotone lattice; single writer per slot; early exit)
    s_r[tid] = (pu < 0 && pi < 0) ? 0 : 255;
    __syncthreads();
    for (int pass = 0; pass < 16; ++pass) {
        if (tid == 0) s_chg = 0;
        __syncthreads();
        if (s_r[tid] == 255) {
            const int ru = pu < 0 ? -1 : (int)s_r[pu];
            const int ri = pi < 0 ? -1 : (int)s_r[pi];
            if (ru != 255 && ri != 255) {
                int rr = 1 + (ru > ri ? ru : ri);
                if (rr > 3) rr = 3;
                s_r[tid] = (unsigned char)rr;
                s_chg = 1;
            }
        }
        __syncthreads();
        if (!s_chg) break;
    }
    const int r = s_r[tid];
    if (r < 3) {
        const int slot = atomicAdd(&cnt[r], 1);
        ws[WS_GL + (r * 32 + b) * 512 + slot] = tid;   // store t
    }
    __syncthreads();
    if (tid < 3) ws[WS_RCNT + tid * 32 + b] = cnt[tid];
    if (tid == 0) {   // late list in t-order (r>=3 incl. unresolved)
        int n = 0;
        for (int t = 0; t < NS; ++t)
            if (s_r[t] >= 3) { ws[WS_LATE + (b << 9) + n] = t; ++n; }
        ws[WS_LCNT + b] = n;
    }
}

// ---- kernel 2: ONE persistent solver for all rounds + late nodes ----
// 256 blocks (= 256 CUs at 90KB LDS -> all resident; spin-wait is safe).
// Global topological virtual-chunk order: v<6144: (r=v>>11, b=(v>>6)&31,
// lc=v&63) chunks of 8 from round lists; v>=6144: late singletons (b=..>>9,
// k=..&511) in per-b t-order. Blocks grid-stride in increasing v.
// Cross-block readiness: per-node flag; producer threadfence+atomicExch,
// consumer atomic-spin + threadfence (only when chunk has parents).
__global__ __launch_bounds__(512, 1) void solve_kernel(
    const int* __restrict__ users, const int* __restrict__ items,
    const float* __restrict__ umem0, const float* __restrict__ imem0,
    const float* __restrict__ b_ih, const float* __restrict__ b_hh,
    int* ws, float* uout, float* iout)
{
    const int tid = threadIdx.x;
    const int lane = tid & 63, wave = tid >> 6;
    const int col = lane & 15, kgrp = lane >> 4;

    __shared__ __align__(16) float yl[16 * 1156];
    __shared__ __align__(16) float xf[16 * 132];
    __shared__ __align__(16) unsigned short xb[16 * 136];
    __shared__ float b6[768];
    __shared__ int s_cnt[128];                 // 96 rcnt + 32 lcnt
    __shared__ unsigned long long srcs[16];
    __shared__ unsigned long long hdst[16];

    for (int i = tid; i < 768; i += 512)
        b6[i] = i < 384 ? b_ih[i] : b_hh[i - 384];
    if (tid < 128) s_cnt[tid] = ws[WS_RCNT + tid];

    const unsigned short* wbf = (const unsigned short*)(ws + WS_WBF);
    bf16x8 wfrag[9][4];
#pragma unroll
    for (int m9 = 0; m9 < 9; ++m9) {
        const int row = wave * 144 + m9 * 16 + col;
#pragma unroll
        for (int kt = 0; kt < 4; ++kt)
            wfrag[m9][kt] = *(const bf16x8*)&wbf[row * 128 + kt * 32 + kgrp * 8];
    }
    __syncthreads();

    for (int v = blockIdx.x; v < 22528; v += 256) {
        int base, n, b;
        if (v < 6144) {
            const int r = v >> 11, lc = v & 63;
            b = (v >> 6) & 31;
            const int cnt = s_cnt[r * 32 + b];
            const int nch = (cnt + 7) >> 3;
            if (lc >= nch) continue;
            base = WS_GL + (r * 32 + b) * 512 + lc * 8;
            n = cnt - lc * 8; if (n > 8) n = 8;
        } else {
            const int v2 = v - 6144, k = v2 & 511;
            b = v2 >> 9;
            if (k >= s_cnt[96 + b]) continue;
            base = WS_LATE + (b << 9) + k;
            n = 1;
        }

        // ---- meta + parent spin (tid<16 -> 2n cols) ----
        int haspar = 0;
        if (tid < 16) {
            const int j = tid >> 1;
            unsigned long long sp = 0, hd = 0;
            if (j < n) {
                const int t = ws[base + j];
                const int node = (b << 9) + t;
                const int cell = tid & 1;
                const int p = ws[(cell ? WS_PREVI : WS_PREVU) + (b << 9) + t];
                const float* s;
                if (p < 0) {
                    const int ix = cell ? items[node] : users[node];
                    s = (cell ? imem0 : umem0) + ((size_t)b * NU + ix) * NE;
                } else {
                    s = (cell ? iout : uout) + ((size_t)((b << 9) + p)) * NE;
                    haspar = 1;
                    int* fp = ws + WS_FLAG + (b << 9) + p;
                    int spins = 0;
                    while (atomicAdd(fp, 0) == 0) {
                        __builtin_amdgcn_s_sleep(2);
                        if (++spins > (1 << 24)) break;   // failsafe, never hit
                    }
                }
                sp = (unsigned long long)s;
                hd = (unsigned long long)((cell ? iout : uout) + (size_t)node * NE);
            }
            srcs[tid] = sp; hdst[tid] = hd;
        }
        if (__syncthreads_count(haspar))   // full barrier + block-wide vote
            __threadfence();               // acquire: parent rows now fresh

        // ---- gather: 32 threads per col, float4 each ----
        {
            const int c = tid >> 5, e4 = (tid & 31) * 4;
            const float* s = (const float*)srcs[c];
            if (s) {
                const float4 vv = *(const float4*)(s + e4);
                *(float4*)&xf[c * 132 + e4] = vv;
                ushort4 w4;
                w4.x = f2bf(vv.x); w4.y = f2bf(vv.y);
                w4.z = f2bf(vv.z); w4.w = f2bf(vv.w);
                *(ushort4*)&xb[c * 136 + e4] = w4;
            }
        }
        BARRIER();

        // ---- MFMA: y[16 cols][1152] = W @ X ----
        {
            bf16x8 bfrag[4];
#pragma unroll
            for (int kt = 0; kt < 4; ++kt)
                bfrag[kt] = *(const bf16x8*)&xb[col * 136 + kt * 32 + kgrp * 8];
            f32x4 acc[9];
#pragma unroll
            for (int m9 = 0; m9 < 9; ++m9) acc[m9] = (f32x4){0.f, 0.f, 0.f, 0.f};
#pragma unroll
            for (int kt = 0; kt < 4; ++kt)
#pragma unroll
                for (int m9 = 0; m9 < 9; ++m9)
                    acc[m9] = __builtin_amdgcn_mfma_f32_16x16x32_bf16(
                        wfrag[m9][kt], bfrag[kt], acc[m9], 0, 0, 0);
#pragma unroll
            for (int m9 = 0; m9 < 9; ++m9)   // D: col=lane&15, row=kgrp*4+reg
                *(f32x4*)&yl[col * 1156 + wave * 144 + m9 * 16 + kgrp * 4] = acc[m9];
        }
        BARRIER();

        // ---- gates + h scatter ----
#pragma unroll
        for (int it = 0; it < 4; ++it) {
            const int idx = tid + it * 512;
            const int c = idx >> 7, e = idx & 127;
            float* hb = (float*)hdst[c];
            if (hb) {
                const float* ys = &yl[c * 1156];
                const float* yo = &yl[(c ^ 1) * 1156];
                const float gir = ys[e]        + yo[384 + e] + b6[e];
                const float giz = ys[128 + e]  + yo[512 + e] + b6[128 + e];
                const float gin = ys[256 + e]  + yo[640 + e] + b6[256 + e];
                const float ghr = ys[768 + e]  + b6[384 + e];
                const float ghz = ys[896 + e]  + b6[512 + e];
                const float ghn = ys[1024 + e] + b6[640 + e];
                const float rr = 1.f / (1.f + __expf(-(gir + ghr)));
                const float z  = 1.f / (1.f + __expf(-(giz + ghz)));
                const float pre = gin + rr * ghn;
                const float nn = 2.f / (1.f + __expf(-2.f * pre)) - 1.f;  // tanh
                hb[e] = (1.f - z) * nn + z * xf[c * 132 + e];
            }
        }

        // ---- publish: release fence, then set node flags ----
        __threadfence();        // h stores device-visible (waits vmcnt, wb L2)
        __syncthreads();
        if (tid < n) {
            const int t = ws[base + tid];
            atomicExch(ws + WS_FLAG + (b << 9) + t, 1);
        }
    }
}

extern "C" void kernel_launch(void* const* d_in, const int* in_sizes, int n_in,
                              void* d_out, int out_size, void* d_ws, size_t ws_size,
                              hipStream_t stream) {
    const int*   users = (const int*)d_in[0];
    const int*   items = (const int*)d_in[1];
    const float* umem0 = (const float*)d_in[2];
    const float* imem0 = (const float*)d_in[3];
    const float* w_ih  = (const float*)d_in[4];
    const float* w_hh  = (const float*)d_in[5];
    const float* b_ih  = (const float*)d_in[6];
    const float* b_hh  = (const float*)d_in[7];

    float* uout = (float*)d_out;
    float* iout = uout + (size_t)NB * NS * NE;
    int* ws = (int*)d_ws;

    prep_kernel<<<68, 512, 0, stream>>>(users, items, w_ih, w_hh, ws);
    solve_kernel<<<256, 512, 0, stream>>>(users, items, umem0, imem0,
                                          b_ih, b_hh, ws, uout, iout);
}

// Round 13
// 148.047 us; speedup vs baseline: 3.5516x; 3.5516x over previous
//
#include <hip/hip_runtime.h>

#define NB 32
#define NS 512
#define NE 128
#define NU 10000

// ---- workspace layout (int units) ----
#define WS_PREVU 0                 // 16384
#define WS_PREVI 16384             // 16384
#define WS_RCNT  32768             // 3*32: per-(round,b) node counts
#define WS_LCNT  32864             // 32: per-b late counts
#define WS_GL    32896             // 3*32*512: per-(round,b) t-lists
#define WS_LATE  82048             // 32*512: per-b late t-lists
#define WS_WBF   98432             // 147456 ushorts (bf16 W_stack)

typedef __attribute__((ext_vector_type(8))) short bf16x8;
typedef __attribute__((ext_vector_type(4))) float f32x4;

__device__ __forceinline__ unsigned short f2bf(float f) {
    unsigned int u = __float_as_uint(f);
    u += 0x7fff + ((u >> 16) & 1);   // round-to-nearest-even
    return (unsigned short)(u >> 16);
}

// ---- kernel 1: per-b prep (blocks 0..31) + W->bf16 (blocks 32..67) ----
__global__ __launch_bounds__(512) void prep_kernel(
    const int* __restrict__ users, const int* __restrict__ items,
    const float* __restrict__ w_ih, const float* __restrict__ w_hh, int* ws)
{
    const int blk = blockIdx.x, tid = threadIdx.x;
    if (blk >= 32) {
        // convw: W_stack row R: R<384 -> w_ih[R,0:128]; R<768 ->
        // w_ih[R-384,128:256]; else w_hh[R-768,:]. 8 elems/thread.
        const int base = (blk - 32) * 4096 + tid * 8;
        const int r = base >> 7, k = base & 127;
        const float* src;
        if (r < 384)      src = w_ih + (size_t)r * 256 + k;
        else if (r < 768) src = w_ih + (size_t)(r - 384) * 256 + 128 + k;
        else              src = w_hh + (size_t)(r - 768) * 128 + k;
        unsigned short* wbf = (unsigned short*)(ws + WS_WBF);
#pragma unroll
        for (int j = 0; j < 8; ++j) wbf[base + j] = f2bf(src[j]);
        return;
    }
    const int b = blk;
    __shared__ int s_u[NS], s_i[NS];
    __shared__ unsigned char s_r[NS];
    __shared__ int cnt[3], s_chg;
    s_u[tid] = users[b * NS + tid];
    s_i[tid] = items[b * NS + tid];
    if (tid < 3) cnt[tid] = 0;
    __syncthreads();
    // backward prev scans, 8-batched to pipeline LDS latency
    const int mu = s_u[tid], mi = s_i[tid];
    int pu = -1, pi = -1;
    for (int u = tid - 1; u >= 0 && pu < 0; u -= 8) {
        int vals[8];
#pragma unroll
        for (int j = 0; j < 8; ++j) {
            const int uu = u - j;
            vals[j] = (uu >= 0) ? s_u[uu] : -1;
        }
#pragma unroll
        for (int j = 0; j < 8; ++j)
            if (pu < 0 && vals[j] == mu) pu = u - j;
    }
    for (int u = tid - 1; u >= 0 && pi < 0; u -= 8) {
        int vals[8];
#pragma unroll
        for (int j = 0; j < 8; ++j) {
            const int uu = u - j;
            vals[j] = (uu >= 0) ? s_i[uu] : -1;
        }
#pragma unroll
        for (int j = 0; j < 8; ++j)
            if (pi < 0 && vals[j] == mi) pi = u - j;
    }
    ws[WS_PREVU + (b << 9) + tid] = pu;
    ws[WS_PREVI + (b << 9) + tid] = pi;
    // round relaxation (monotone lattice; single writer per slot; early exit)
    s_r[tid] = (pu < 0 && pi < 0) ? 0 : 255;
    __syncthreads();
    for (int pass = 0; pass < 16; ++pass) {
        if (tid == 0) s_chg = 0;
        __syncthreads();
        if (s_r[tid] == 255) {
            const int ru = pu < 0 ? -1 : (int)s_r[pu];
            const int ri = pi < 0 ? -1 : (int)s_r[pi];
            if (ru != 255 && ri != 255) {
                int rr = 1 + (ru > ri ? ru : ri);
                if (rr > 3) rr = 3;
                s_r[tid] = (unsigned char)rr;
                s_chg = 1;
            }
        }
        __syncthreads();
        if (!s_chg) break;
    }
    const int r = s_r[tid];
    if (r < 3) {
        const int slot = atomicAdd(&cnt[r], 1);
        ws[WS_GL + (r * 32 + b) * 512 + slot] = tid;   // store t
    }
    __syncthreads();
    if (tid < 3) ws[WS_RCNT + tid * 32 + b] = cnt[tid];
    if (tid == 0) {   // late list in t-order (r>=3 incl. unresolved)
        int n = 0;
        for (int t = 0; t < NS; ++t)
            if (s_r[t] >= 3) { ws[WS_LATE + (b << 9) + n] = t; ++n; }
        ws[WS_LCNT + b] = n;
    }
}

// ---- kernel 2: round-0 batched GEMM+gates (~95% of nodes) ----
// 256 blocks: b = blk&31, sblk = blk>>5 handles b's chunks sblk, sblk+8,...
// r0 nodes have NO parents: sources are pure mem0 rows (no prev reads).
__global__ __launch_bounds__(512, 1) void rg0_kernel(
    const int* __restrict__ users, const int* __restrict__ items,
    const float* __restrict__ umem0, const float* __restrict__ imem0,
    const float* __restrict__ b_ih, const float* __restrict__ b_hh,
    const int* __restrict__ ws, float* uout, float* iout)
{
    const int b = blockIdx.x & 31, sblk = blockIdx.x >> 5;
    const int cnt = ws[WS_RCNT + b];          // r = 0
    const int nch = (cnt + 7) >> 3;
    if (sblk >= nch) return;
    const int tid = threadIdx.x;
    const int lane = tid & 63, wave = tid >> 6;
    const int col = lane & 15, kgrp = lane >> 4;

    __shared__ __align__(16) float yl[16 * 1156];
    __shared__ __align__(16) float xf[16 * 132];
    __shared__ __align__(16) unsigned short xb[16 * 136];
    __shared__ float b6[768];
    __shared__ unsigned long long srcs[16];
    __shared__ unsigned long long hdst[16];

    for (int i = tid; i < 768; i += 512)
        b6[i] = i < 384 ? b_ih[i] : b_hh[i - 384];

    const unsigned short* wbf = (const unsigned short*)(ws + WS_WBF);
    bf16x8 wfrag[9][4];
#pragma unroll
    for (int m9 = 0; m9 < 9; ++m9) {
        const int row = wave * 144 + m9 * 16 + col;
#pragma unroll
        for (int kt = 0; kt < 4; ++kt)
            wfrag[m9][kt] = *(const bf16x8*)&wbf[row * 128 + kt * 32 + kgrp * 8];
    }

    const int* glist = ws + WS_GL + b * 512;   // (0*32 + b) * 512

    for (int lc = sblk; lc < nch; lc += 8) {
        if (tid < 16) {
            const int j = lc * 8 + (tid >> 1);
            unsigned long long sp = 0, hd = 0;
            if (j < cnt) {
                const int t = glist[j];
                const int node = (b << 9) + t;
                const int cell = tid & 1;
                const int ix = cell ? items[node] : users[node];
                sp = (unsigned long long)((cell ? imem0 : umem0)
                                          + ((size_t)b * NU + ix) * NE);
                hd = (unsigned long long)((cell ? iout : uout) + (size_t)node * NE);
            }
            srcs[tid] = sp; hdst[tid] = hd;
        }
        __syncthreads();
        {
            const int c = tid >> 5, e4 = (tid & 31) * 4;
            const float* s = (const float*)srcs[c];
            if (s) {
                const float4 vv = *(const float4*)(s + e4);
                *(float4*)&xf[c * 132 + e4] = vv;
                ushort4 w4;
                w4.x = f2bf(vv.x); w4.y = f2bf(vv.y);
                w4.z = f2bf(vv.z); w4.w = f2bf(vv.w);
                *(ushort4*)&xb[c * 136 + e4] = w4;
            }
        }
        __syncthreads();
        {
            bf16x8 bfrag[4];
#pragma unroll
            for (int kt = 0; kt < 4; ++kt)
                bfrag[kt] = *(const bf16x8*)&xb[col * 136 + kt * 32 + kgrp * 8];
            f32x4 acc[9];
#pragma unroll
            for (int m9 = 0; m9 < 9; ++m9) acc[m9] = (f32x4){0.f, 0.f, 0.f, 0.f};
#pragma unroll
            for (int kt = 0; kt < 4; ++kt)
#pragma unroll
                for (int m9 = 0; m9 < 9; ++m9)
                    acc[m9] = __builtin_amdgcn_mfma_f32_16x16x32_bf16(
                        wfrag[m9][kt], bfrag[kt], acc[m9], 0, 0, 0);
#pragma unroll
            for (int m9 = 0; m9 < 9; ++m9)   // D: col=lane&15, row=kgrp*4+reg
                *(f32x4*)&yl[col * 1156 + wave * 144 + m9 * 16 + kgrp * 4] = acc[m9];
        }
        __syncthreads();
#pragma unroll
        for (int it = 0; it < 4; ++it) {
            const int idx = tid + it * 512;
            const int c = idx >> 7, e = idx & 127;
            float* hb = (float*)hdst[c];
            if (hb) {
                const float* ys = &yl[c * 1156];
                const float* yo = &yl[(c ^ 1) * 1156];
                const float gir = ys[e]        + yo[384 + e] + b6[e];
                const float giz = ys[128 + e]  + yo[512 + e] + b6[128 + e];
                const float gin = ys[256 + e]  + yo[640 + e] + b6[256 + e];
                const float ghr = ys[768 + e]  + b6[384 + e];
                const float ghz = ys[896 + e]  + b6[512 + e];
                const float ghn = ys[1024 + e] + b6[640 + e];
                const float rr = 1.f / (1.f + __expf(-(gir + ghr)));
                const float z  = 1.f / (1.f + __expf(-(giz + ghz)));
                const float pre = gin + rr * ghn;
                const float nn = 2.f / (1.f + __expf(-2.f * pre)) - 1.f;  // tanh
                hb[e] = (1.f - z) * nn + z * xf[c * 132 + e];
            }
        }
        __syncthreads();
    }
}

// ---- kernel 3: per-b finish: r1 chunks, r2 chunks, late singles ----
// All dependencies are within-b. Parents are r0 (prior dispatch) or values
// this block itself wrote (same CU; threadfence+syncthreads per chunk).
__global__ __launch_bounds__(512, 1) void finish_kernel(
    const int* __restrict__ users, const int* __restrict__ items,
    const float* __restrict__ umem0, const float* __restrict__ imem0,
    const float* __restrict__ b_ih, const float* __restrict__ b_hh,
    const int* __restrict__ ws, float* uout, float* iout)
{
    const int b = blockIdx.x;
    const int tid = threadIdx.x;
    const int lane = tid & 63, wave = tid >> 6;
    const int col = lane & 15, kgrp = lane >> 4;

    const int cnt1 = ws[WS_RCNT + 32 + b];
    const int cnt2 = ws[WS_RCNT + 64 + b];
    const int cntL = ws[WS_LCNT + b];
    if (cnt1 + cnt2 + cntL == 0) return;

    __shared__ __align__(16) float yl[16 * 1156];
    __shared__ __align__(16) float xf[16 * 132];
    __shared__ __align__(16) unsigned short xb[16 * 136];
    __shared__ float b6[768];
    __shared__ unsigned long long srcs[16];
    __shared__ unsigned long long hdst[16];

    for (int i = tid; i < 768; i += 512)
        b6[i] = i < 384 ? b_ih[i] : b_hh[i - 384];

    const unsigned short* wbf = (const unsigned short*)(ws + WS_WBF);
    bf16x8 wfrag[9][4];
#pragma unroll
    for (int m9 = 0; m9 < 9; ++m9) {
        const int row = wave * 144 + m9 * 16 + col;
#pragma unroll
        for (int kt = 0; kt < 4; ++kt)
            wfrag[m9][kt] = *(const bf16x8*)&wbf[row * 128 + kt * 32 + kgrp * 8];
    }

    const int* prevU = ws + WS_PREVU + (b << 9);
    const int* prevI = ws + WS_PREVI + (b << 9);

    for (int ph = 0; ph < 3; ++ph) {
        int base, cntn, step;
        if (ph == 0)      { cntn = cnt1; base = WS_GL + (32 + b) * 512;  step = 8; }
        else if (ph == 1) { cntn = cnt2; base = WS_GL + (64 + b) * 512;  step = 8; }
        else              { cntn = cntL; base = WS_LATE + (b << 9);      step = 1; }
        for (int j0 = 0; j0 < cntn; j0 += step) {
            const int n = (cntn - j0 < step) ? (cntn - j0) : step;
            if (tid < 16) {
                const int jj = tid >> 1;
                unsigned long long sp = 0, hd = 0;
                if (jj < n) {
                    const int t = ws[base + j0 + jj];
                    const int node = (b << 9) + t;
                    const int cell = tid & 1;
                    const int p = cell ? prevI[t] : prevU[t];
                    const float* s;
                    if (p < 0) {
                        const int ix = cell ? items[node] : users[node];
                        s = (cell ? imem0 : umem0) + ((size_t)b * NU + ix) * NE;
                    } else {
                        s = (cell ? iout : uout) + ((size_t)((b << 9) + p)) * NE;
                    }
                    sp = (unsigned long long)s;
                    hd = (unsigned long long)((cell ? iout : uout) + (size_t)node * NE);
                }
                srcs[tid] = sp; hdst[tid] = hd;
            }
            __syncthreads();
            {
                const int c = tid >> 5, e4 = (tid & 31) * 4;
                const float* s = (const float*)srcs[c];
                if (s) {
                    const float4 vv = *(const float4*)(s + e4);
                    *(float4*)&xf[c * 132 + e4] = vv;
                    ushort4 w4;
                    w4.x = f2bf(vv.x); w4.y = f2bf(vv.y);
                    w4.z = f2bf(vv.z); w4.w = f2bf(vv.w);
                    *(ushort4*)&xb[c * 136 + e4] = w4;
                }
            }
            __syncthreads();
            {
                bf16x8 bfrag[4];
#pragma unroll
                for (int kt = 0; kt < 4; ++kt)
                    bfrag[kt] = *(const bf16x8*)&xb[col * 136 + kt * 32 + kgrp * 8];
                f32x4 acc[9];
#pragma unroll
                for (int m9 = 0; m9 < 9; ++m9) acc[m9] = (f32x4){0.f, 0.f, 0.f, 0.f};
#pragma unroll
                for (int kt = 0; kt < 4; ++kt)
#pragma unroll
                    for (int m9 = 0; m9 < 9; ++m9)
                        acc[m9] = __builtin_amdgcn_mfma_f32_16x16x32_bf16(
                            wfrag[m9][kt], bfrag[kt], acc[m9], 0, 0, 0);
#pragma unroll
                for (int m9 = 0; m9 < 9; ++m9)
                    *(f32x4*)&yl[col * 1156 + wave * 144 + m9 * 16 + kgrp * 4] = acc[m9];
            }
            __syncthreads();
#pragma unroll
            for (int it = 0; it < 4; ++it) {
                const int idx = tid + it * 512;
                const int c = idx >> 7, e = idx & 127;
                float* hb = (float*)hdst[c];
                if (hb) {
                    const float* ys = &yl[c * 1156];
                    const float* yo = &yl[(c ^ 1) * 1156];
                    const float gir = ys[e]        + yo[384 + e] + b6[e];
                    const float giz = ys[128 + e]  + yo[512 + e] + b6[128 + e];
                    const float gin = ys[256 + e]  + yo[640 + e] + b6[256 + e];
                    const float ghr = ys[768 + e]  + b6[384 + e];
                    const float ghz = ys[896 + e]  + b6[512 + e];
                    const float ghn = ys[1024 + e] + b6[640 + e];
                    const float rr = 1.f / (1.f + __expf(-(gir + ghr)));
                    const float z  = 1.f / (1.f + __expf(-(giz + ghz)));
                    const float pre = gin + rr * ghn;
                    const float nn = 2.f / (1.f + __expf(-2.f * pre)) - 1.f;
                    hb[e] = (1.f - z) * nn + z * xf[c * 132 + e];
                }
            }
            __threadfence();   // ~9 total per block: cheap at this count
            __syncthreads();
        }
    }
}

extern "C" void kernel_launch(void* const* d_in, const int* in_sizes, int n_in,
                              void* d_out, int out_size, void* d_ws, size_t ws_size,
                              hipStream_t stream) {
    const int*   users = (const int*)d_in[0];
    const int*   items = (const int*)d_in[1];
    const float* umem0 = (const float*)d_in[2];
    const float* imem0 = (const float*)d_in[3];
    const float* w_ih  = (const float*)d_in[4];
    const float* w_hh  = (const float*)d_in[5];
    const float* b_ih  = (const float*)d_in[6];
    const float* b_hh  = (const float*)d_in[7];

    float* uout = (float*)d_out;
    float* iout = uout + (size_t)NB * NS * NE;
    int* ws = (int*)d_ws;

    prep_kernel<<<68, 512, 0, stream>>>(users, items, w_ih, w_hh, ws);
    rg0_kernel<<<256, 512, 0, stream>>>(users, items, umem0, imem0,
                                        b_ih, b_hh, ws, uout, iout);
    finish_kernel<<<NB, 512, 0, stream>>>(users, items, umem0, imem0,
                                          b_ih, b_hh, ws, uout, iout);
}

// Round 14
// 125.654 us; speedup vs baseline: 4.1845x; 1.1782x over previous
//
#include <hip/hip_runtime.h>

#define NB 32
#define NS 512
#define NE 128
#define NU 10000

// ---- workspace layout (int units) ----
#define WS_PREVU 0                 // 16384
#define WS_PREVI 16384             // 16384
#define WS_RCNT  32768             // 3*32: per-(round,b) node counts
#define WS_LCNT  32864             // 32: per-b late counts
#define WS_GL    32896             // 3*32*512: per-(round,b) t-lists
#define WS_LATE  82048             // 32*512: per-b late t-lists
#define WS_WBF   98432             // 147456 ushorts (bf16 W_stack)

typedef __attribute__((ext_vector_type(8))) short bf16x8;
typedef __attribute__((ext_vector_type(4))) float f32x4;

__device__ __forceinline__ unsigned short f2bf(float f) {
    unsigned int u = __float_as_uint(f);
    u += 0x7fff + ((u >> 16) & 1);   // round-to-nearest-even
    return (unsigned short)(u >> 16);
}

// LDS-only barrier (no vmcnt drain; global loads/stores stay in flight).
#define BARRIER() do { \
    asm volatile("s_waitcnt lgkmcnt(0)" ::: "memory"); \
    __builtin_amdgcn_s_barrier(); \
    __builtin_amdgcn_sched_barrier(0); \
} while (0)

// ---- kernel 1: prep. Blocks 0..31: per-b dual prev-scan (interleaved, ILP)
// + round relaxation + list build. Blocks 32..67: W->bf16 conversion. ----
__global__ __launch_bounds__(512) void prep_kernel(
    const int* __restrict__ users, const int* __restrict__ items,
    const float* __restrict__ w_ih, const float* __restrict__ w_hh, int* ws)
{
    const int blk = blockIdx.x, tid = threadIdx.x;
    if (blk >= 32) {
        // convw: W_stack row R: R<384 -> w_ih[R,0:128]; R<768 ->
        // w_ih[R-384,128:256]; else w_hh[R-768,:]. 8 elems/thread.
        const int base = (blk - 32) * 4096 + tid * 8;
        const int r = base >> 7, k = base & 127;
        const float* src;
        if (r < 384)      src = w_ih + (size_t)r * 256 + k;
        else if (r < 768) src = w_ih + (size_t)(r - 384) * 256 + 128 + k;
        else              src = w_hh + (size_t)(r - 768) * 128 + k;
        unsigned short* wbf = (unsigned short*)(ws + WS_WBF);
#pragma unroll
        for (int j = 0; j < 8; ++j) wbf[base + j] = f2bf(src[j]);
        return;
    }
    const int b = blk;
    __shared__ int s_u[NS], s_i[NS];
    __shared__ unsigned char s_r[NS];
    __shared__ int cnt[3], s_chg;
    s_u[tid] = users[b * NS + tid];
    s_i[tid] = items[b * NS + tid];
    if (tid < 3) cnt[tid] = 0;
    __syncthreads();
    // dual backward scan, INTERLEAVED (16 independent LDS reads/iter ->
    // the second table's scan costs ~0 extra latency vs one scan)
    const int mu = s_u[tid], mi = s_i[tid];
    int pu = -1, pi = -1;
    for (int u = tid - 1; u >= 0 && ((pu < 0) | (pi < 0)); u -= 8) {
        int vu[8], vi[8];
#pragma unroll
        for (int j = 0; j < 8; ++j) {
            const int uu = u - j;
            vu[j] = (uu >= 0) ? s_u[uu] : -1;
            vi[j] = (uu >= 0) ? s_i[uu] : -1;
        }
#pragma unroll
        for (int j = 0; j < 8; ++j) {
            if (pu < 0 && vu[j] == mu) pu = u - j;
            if (pi < 0 && vi[j] == mi) pi = u - j;
        }
    }
    ws[WS_PREVU + (b << 9) + tid] = pu;
    ws[WS_PREVI + (b << 9) + tid] = pi;
    // round relaxation (monotone lattice; single writer per slot; early exit)
    s_r[tid] = (pu < 0 && pi < 0) ? 0 : 255;
    __syncthreads();
    for (int pass = 0; pass < 16; ++pass) {
        if (tid == 0) s_chg = 0;
        __syncthreads();
        if (s_r[tid] == 255) {
            const int ru = pu < 0 ? -1 : (int)s_r[pu];
            const int ri = pi < 0 ? -1 : (int)s_r[pi];
            if (ru != 255 && ri != 255) {
                int rr = 1 + (ru > ri ? ru : ri);
                if (rr > 3) rr = 3;
                s_r[tid] = (unsigned char)rr;
                s_chg = 1;
            }
        }
        __syncthreads();
        if (!s_chg) break;
    }
    const int r = s_r[tid];
    if (r < 3) {
        const int slot = atomicAdd(&cnt[r], 1);
        ws[WS_GL + (r * 32 + b) * 512 + slot] = tid;   // store t
    }
    __syncthreads();
    if (tid < 3) ws[WS_RCNT + tid * 32 + b] = cnt[tid];
    if (tid == 0) {   // late list in t-order (r>=3 incl. unresolved)
        int n = 0;
        for (int t = 0; t < NS; ++t)
            if (s_r[t] >= 3) { ws[WS_LATE + (b << 9) + n] = t; ++n; }
        ws[WS_LCNT + b] = n;
    }
}

// ---- kernel 2: batched GEMM+gates for round r, T14-pipelined ----
// 256 blocks: b = blk&31, sblk = blk>>5 walks b's chunks sblk, sblk+8, ...
// Pipeline: while chunk k computes (MFMA+gates), chunk k+1's meta is built
// and its gather issued; LDS-only barriers keep the loads in flight.
// No intra-dispatch dependencies (round-(r) parents are all round < r).
__global__ __launch_bounds__(512, 1) void rg_kernel(
    const int* __restrict__ users, const int* __restrict__ items,
    const float* __restrict__ umem0, const float* __restrict__ imem0,
    const float* __restrict__ b_ih, const float* __restrict__ b_hh,
    const int* __restrict__ ws, float* uout, float* iout, int r)
{
    const int b = blockIdx.x & 31, sblk = blockIdx.x >> 5;
    const int cnt = ws[WS_RCNT + r * 32 + b];
    const int nch = (cnt + 7) >> 3;
    if (sblk >= nch) return;
    const int tid = threadIdx.x;
    const int lane = tid & 63, wave = tid >> 6;
    const int col = lane & 15, kgrp = lane >> 4;

    __shared__ __align__(16) float yl[16 * 1156];
    __shared__ __align__(16) float xf[16 * 132];
    __shared__ __align__(16) unsigned short xb[16 * 136];
    __shared__ float b6[768];
    __shared__ unsigned long long srcs[2][16];
    __shared__ unsigned long long hdst[2][16];

    for (int i = tid; i < 768; i += 512)
        b6[i] = i < 384 ? b_ih[i] : b_hh[i - 384];

    const unsigned short* wbf = (const unsigned short*)(ws + WS_WBF);
    bf16x8 wfrag[9][4];
#pragma unroll
    for (int m9 = 0; m9 < 9; ++m9) {
        const int row = wave * 144 + m9 * 16 + col;
#pragma unroll
        for (int kt = 0; kt < 4; ++kt)
            wfrag[m9][kt] = *(const bf16x8*)&wbf[row * 128 + kt * 32 + kgrp * 8];
    }

    const int* glist = ws + WS_GL + (r * 32 + b) * 512;
    const int* prevU = ws + WS_PREVU + (b << 9);
    const int* prevI = ws + WS_PREVI + (b << 9);

#define META(LC, SEL) do { \
    if (tid < 16) { \
        const int j = (LC) * 8 + (tid >> 1); \
        unsigned long long sp = 0, hd = 0; \
        if (j < cnt) { \
            const int t = glist[j]; \
            const int node = (b << 9) + t; \
            const int cell = tid & 1; \
            const int p = cell ? prevI[t] : prevU[t]; \
            const float* s; \
            if (p < 0) { \
                const int ix = cell ? items[node] : users[node]; \
                s = (cell ? imem0 : umem0) + ((size_t)b * NU + ix) * NE; \
            } else { \
                s = (cell ? iout : uout) + ((size_t)((b << 9) + p)) * NE; \
            } \
            sp = (unsigned long long)s; \
            hd = (unsigned long long)((cell ? iout : uout) + (size_t)node * NE); \
        } \
        srcs[SEL][tid] = sp; hdst[SEL][tid] = hd; \
    } \
} while (0)

    const int gc = tid >> 5, ge4 = (tid & 31) * 4;
    int cur = 0;
    META(sblk, 0);
    BARRIER();
    float4 v = (float4){0.f, 0.f, 0.f, 0.f};
    {   // prologue gather for first chunk
        const float* s = (const float*)srcs[0][gc];
        if (s) v = *(const float4*)(s + ge4);
    }

    for (int lc = sblk; lc < nch; lc += 8) {
        const int nxt = cur ^ 1;
        const bool hasnext = (lc + 8) < nch;
        if (hasnext) META(lc + 8, nxt);       // build next meta (tid<16)
        // stage current chunk's x (v regs -> LDS)
        if (hdst[cur][gc]) {
            *(float4*)&xf[gc * 132 + ge4] = v;
            ushort4 w4;
            w4.x = f2bf(v.x); w4.y = f2bf(v.y);
            w4.z = f2bf(v.z); w4.w = f2bf(v.w);
            *(ushort4*)&xb[gc * 136 + ge4] = w4;
        }
        BARRIER();                            // xb/xf + srcs[nxt] visible
        float4 vn = (float4){0.f, 0.f, 0.f, 0.f};
        if (hasnext) {                        // issue next gather NOW; it
            const float* s = (const float*)srcs[nxt][gc];   // retires under
            if (s) vn = *(const float4*)(s + ge4);          // MFMA+gates
        }
        // MFMA: y[16 cols][1152] = W @ X
        {
            bf16x8 bfrag[4];
#pragma unroll
            for (int kt = 0; kt < 4; ++kt)
                bfrag[kt] = *(const bf16x8*)&xb[col * 136 + kt * 32 + kgrp * 8];
            f32x4 acc[9];
#pragma unroll
            for (int m9 = 0; m9 < 9; ++m9) acc[m9] = (f32x4){0.f, 0.f, 0.f, 0.f};
#pragma unroll
            for (int kt = 0; kt < 4; ++kt)
#pragma unroll
                for (int m9 = 0; m9 < 9; ++m9)
                    acc[m9] = __builtin_amdgcn_mfma_f32_16x16x32_bf16(
                        wfrag[m9][kt], bfrag[kt], acc[m9], 0, 0, 0);
#pragma unroll
            for (int m9 = 0; m9 < 9; ++m9)   // D: col=lane&15, row=kgrp*4+reg
                *(f32x4*)&yl[col * 1156 + wave * 144 + m9 * 16 + kgrp * 4] = acc[m9];
        }
        BARRIER();
        // gates + h scatter
#pragma unroll
        for (int it = 0; it < 4; ++it) {
            const int idx = tid + it * 512;
            const int c = idx >> 7, e = idx & 127;
            float* hb = (float*)hdst[cur][c];
            if (hb) {
                const float* ys = &yl[c * 1156];
                const float* yo = &yl[(c ^ 1) * 1156];
                const float gir = ys[e]        + yo[384 + e] + b6[e];
                const float giz = ys[128 + e]  + yo[512 + e] + b6[128 + e];
                const float gin = ys[256 + e]  + yo[640 + e] + b6[256 + e];
                const float ghr = ys[768 + e]  + b6[384 + e];
                const float ghz = ys[896 + e]  + b6[512 + e];
                const float ghn = ys[1024 + e] + b6[640 + e];
                const float rr = 1.f / (1.f + __expf(-(gir + ghr)));
                const float z  = 1.f / (1.f + __expf(-(giz + ghz)));
                const float pre = gin + rr * ghn;
                const float nn = 2.f / (1.f + __expf(-2.f * pre)) - 1.f;  // tanh
                hb[e] = (1.f - z) * nn + z * xf[c * 132 + e];
            }
        }
        BARRIER();      // protects xf/xb/srcs[cur]/hdst[cur] for next iter
        v = vn; cur = nxt;
    }
#undef META
}

// ---- kernel 3: cleanup — r2 chunks + late singles, serial per b ----
// Parents: rounds 0/1 (prior dispatches) or this block's own prior writes
// (same CU/L2; threadfence+syncthreads per chunk; ~1-2 chunks per b total).
__global__ __launch_bounds__(512, 1) void cleanup_kernel(
    const int* __restrict__ users, const int* __restrict__ items,
    const float* __restrict__ umem0, const float* __restrict__ imem0,
    const float* __restrict__ b_ih, const float* __restrict__ b_hh,
    const int* __restrict__ ws, float* uout, float* iout)
{
    const int b = blockIdx.x;
    const int cnt2 = ws[WS_RCNT + 64 + b];
    const int cntL = ws[WS_LCNT + b];
    if (cnt2 + cntL == 0) return;
    const int tid = threadIdx.x;
    const int lane = tid & 63, wave = tid >> 6;
    const int col = lane & 15, kgrp = lane >> 4;

    __shared__ __align__(16) float yl[16 * 1156];
    __shared__ __align__(16) float xf[16 * 132];
    __shared__ __align__(16) unsigned short xb[16 * 136];
    __shared__ float b6[768];
    __shared__ unsigned long long srcs[16];
    __shared__ unsigned long long hdst[16];

    for (int i = tid; i < 768; i += 512)
        b6[i] = i < 384 ? b_ih[i] : b_hh[i - 384];

    const unsigned short* wbf = (const unsigned short*)(ws + WS_WBF);
    bf16x8 wfrag[9][4];
#pragma unroll
    for (int m9 = 0; m9 < 9; ++m9) {
        const int row = wave * 144 + m9 * 16 + col;
#pragma unroll
        for (int kt = 0; kt < 4; ++kt)
            wfrag[m9][kt] = *(const bf16x8*)&wbf[row * 128 + kt * 32 + kgrp * 8];
    }

    const int* prevU = ws + WS_PREVU + (b << 9);
    const int* prevI = ws + WS_PREVI + (b << 9);

    for (int ph = 0; ph < 2; ++ph) {
        const int cntn = ph == 0 ? cnt2 : cntL;
        const int base = ph == 0 ? WS_GL + (64 + b) * 512 : WS_LATE + (b << 9);
        const int step = ph == 0 ? 8 : 1;
        for (int j0 = 0; j0 < cntn; j0 += step) {
            const int n = (cntn - j0 < step) ? (cntn - j0) : step;
            if (tid < 16) {
                const int jj = tid >> 1;
                unsigned long long sp = 0, hd = 0;
                if (jj < n) {
                    const int t = ws[base + j0 + jj];
                    const int node = (b << 9) + t;
                    const int cell = tid & 1;
                    const int p = cell ? prevI[t] : prevU[t];
                    const float* s;
                    if (p < 0) {
                        const int ix = cell ? items[node] : users[node];
                        s = (cell ? imem0 : umem0) + ((size_t)b * NU + ix) * NE;
                    } else {
                        s = (cell ? iout : uout) + ((size_t)((b << 9) + p)) * NE;
                    }
                    sp = (unsigned long long)s;
                    hd = (unsigned long long)((cell ? iout : uout) + (size_t)node * NE);
                }
                srcs[tid] = sp; hdst[tid] = hd;
            }
            __syncthreads();
            {
                const int c = tid >> 5, e4 = (tid & 31) * 4;
                const float* s = (const float*)srcs[c];
                if (s) {
                    const float4 vv = *(const float4*)(s + e4);
                    *(float4*)&xf[c * 132 + e4] = vv;
                    ushort4 w4;
                    w4.x = f2bf(vv.x); w4.y = f2bf(vv.y);
                    w4.z = f2bf(vv.z); w4.w = f2bf(vv.w);
                    *(ushort4*)&xb[c * 136 + e4] = w4;
                }
            }
            __syncthreads();
            {
                bf16x8 bfrag[4];
#pragma unroll
                for (int kt = 0; kt < 4; ++kt)
                    bfrag[kt] = *(const bf16x8*)&xb[col * 136 + kt * 32 + kgrp * 8];
                f32x4 acc[9];
#pragma unroll
                for (int m9 = 0; m9 < 9; ++m9) acc[m9] = (f32x4){0.f, 0.f, 0.f, 0.f};
#pragma unroll
                for (int kt = 0; kt < 4; ++kt)
#pragma unroll
                    for (int m9 = 0; m9 < 9; ++m9)
                        acc[m9] = __builtin_amdgcn_mfma_f32_16x16x32_bf16(
                            wfrag[m9][kt], bfrag[kt], acc[m9], 0, 0, 0);
#pragma unroll
                for (int m9 = 0; m9 < 9; ++m9)
                    *(f32x4*)&yl[col * 1156 + wave * 144 + m9 * 16 + kgrp * 4] = acc[m9];
            }
            __syncthreads();
#pragma unroll
            for (int it = 0; it < 4; ++it) {
                const int idx = tid + it * 512;
                const int c = idx >> 7, e = idx & 127;
                float* hb = (float*)hdst[c];
                if (hb) {
                    const float* ys = &yl[c * 1156];
                    const float* yo = &yl[(c ^ 1) * 1156];
                    const float gir = ys[e]        + yo[384 + e] + b6[e];
                    const float giz = ys[128 + e]  + yo[512 + e] + b6[128 + e];
                    const float gin = ys[256 + e]  + yo[640 + e] + b6[256 + e];
                    const float ghr = ys[768 + e]  + b6[384 + e];
                    const float ghz = ys[896 + e]  + b6[512 + e];
                    const float ghn = ys[1024 + e] + b6[640 + e];
                    const float rr = 1.f / (1.f + __expf(-(gir + ghr)));
                    const float z  = 1.f / (1.f + __expf(-(giz + ghz)));
                    const float pre = gin + rr * ghn;
                    const float nn = 2.f / (1.f + __expf(-2.f * pre)) - 1.f;
                    hb[e] = (1.f - z) * nn + z * xf[c * 132 + e];
                }
            }
            __threadfence();
            __syncthreads();
        }
    }
}

extern "C" void kernel_launch(void* const* d_in, const int* in_sizes, int n_in,
                              void* d_out, int out_size, void* d_ws, size_t ws_size,
                              hipStream_t stream) {
    const int*   users = (const int*)d_in[0];
    const int*   items = (const int*)d_in[1];
    const float* umem0 = (const float*)d_in[2];
    const float* imem0 = (const float*)d_in[3];
    const float* w_ih  = (const float*)d_in[4];
    const float* w_hh  = (const float*)d_in[5];
    const float* b_ih  = (const float*)d_in[6];
    const float* b_hh  = (const float*)d_in[7];

    float* uout = (float*)d_out;
    float* iout = uout + (size_t)NB * NS * NE;
    int* ws = (int*)d_ws;

    prep_kernel<<<68, 512, 0, stream>>>(users, items, w_ih, w_hh, ws);
    rg_kernel<<<256, 512, 0, stream>>>(users, items, umem0, imem0,
                                       b_ih, b_hh, ws, uout, iout, 0);
    rg_kernel<<<256, 512, 0, stream>>>(users, items, umem0, imem0,
                                       b_ih, b_hh, ws, uout, iout, 1);
    cleanup_kernel<<<NB, 512, 0, stream>>>(users, items, umem0, imem0,
                                           b_ih, b_hh, ws, uout, iout);
}